// Round 7
// baseline (1223.763 us; speedup 1.0000x reference)
//
#include <hip/hip_runtime.h>
#include <hip/hip_bf16.h>
#include <stdint.h>

#define BB 8
#define TT 168
#define NN 1024
#define BN_ 8192
#define FD_ 16
#define EE 16384
#define NBLK 512

typedef short short8 __attribute__((ext_vector_type(8)));
typedef __bf16 bf16x8 __attribute__((ext_vector_type(8)));
typedef float f32x4 __attribute__((ext_vector_type(4)));

#if __has_builtin(__builtin_amdgcn_exp2f)
#define EXP2(x) __builtin_amdgcn_exp2f(x)
#else
#define EXP2(x) exp2f(x)
#endif
#if __has_builtin(__builtin_amdgcn_rcpf)
#define RCPF(x) __builtin_amdgcn_rcpf(x)
#else
#define RCPF(x) (1.f / (x))
#endif
#define L2E 1.4426950408889634f
#define T2E 2.8853900817779268f

static __device__ __forceinline__ float b2f(ushort s) {
    unsigned u = ((unsigned)s) << 16;
    return __builtin_bit_cast(float, u);
}
static __device__ __forceinline__ ushort f2b(float f) {      // RNE
    unsigned u = __builtin_bit_cast(unsigned, f);
    unsigned lsb = (u >> 16) & 1u;
    u += 0x7fffu + lsb;
    return (ushort)(u >> 16);
}
static __device__ __forceinline__ ushort f2b_fast(float f) {
    unsigned u = __builtin_bit_cast(unsigned, f);
    return (ushort)((u + 0x8000u) >> 16);
}
static __device__ __forceinline__ f32x4 mfma16(short8 a, short8 b, f32x4 c) {
    return __builtin_amdgcn_mfma_f32_16x16x32_bf16(
        __builtin_bit_cast(bf16x8, a), __builtin_bit_cast(bf16x8, b), c, 0, 0, 0);
}

// bf16 weight cache layout (ushort offsets)
#define O_WIH 0
#define O_WHH 8192
#define O_STA 73728
#define O_FCS 335872
#define O_SW  401408
#define O_FW  405504
#define O_UW  406528
#define O_G0W 455680
#define O_G1W 521216
#define O_END 586752

// ---------------------------------------------------------------------------
// Software grid barrier: generation-counter, agent scope. All NBLK blocks
// are co-resident by construction (launch_bounds(256,2): capacity >= 512).
// ---------------------------------------------------------------------------
static __device__ __forceinline__ void gridbar(int* bar) {
    __syncthreads();
    if (threadIdx.x == 0) {
        __threadfence();
        int* cnt = bar;
        int* gen = bar + 16;
        const int g = __hip_atomic_load(gen, __ATOMIC_RELAXED, __HIP_MEMORY_SCOPE_AGENT);
        const int a = __hip_atomic_fetch_add(cnt, 1, __ATOMIC_ACQ_REL, __HIP_MEMORY_SCOPE_AGENT);
        if (a == NBLK - 1) {
            __hip_atomic_store(cnt, 0, __ATOMIC_RELAXED, __HIP_MEMORY_SCOPE_AGENT);
            __hip_atomic_fetch_add(gen, 1, __ATOMIC_RELEASE, __HIP_MEMORY_SCOPE_AGENT);
        } else {
            while (__hip_atomic_load(gen, __ATOMIC_RELAXED, __HIP_MEMORY_SCOPE_AGENT) == g)
                __builtin_amdgcn_s_sleep(8);
            (void)__hip_atomic_load(gen, __ATOMIC_ACQUIRE, __HIP_MEMORY_SCOPE_AGENT);
        }
    }
    __syncthreads();
}

// ---------------------------------------------------------------------------
// gemmatt stage: block = 16 rows, wave w = head w. xl head-interleaved:
// xl[node*512 + c*4 + h].
// ---------------------------------------------------------------------------
static __device__ void gemmatt_stage(int bid, int tid, const ushort* hB,
                                     const ushort* W, const float* asrc,
                                     const float* adst, ushort* xl,
                                     float* as_, float* ad_) {
    const int lane = tid & 63, quad = lane >> 4, m = lane & 15;
    const int w = tid >> 6;
    const int r0 = bid * 16;
    f32x4 acc[8];
#pragma unroll
    for (int ct = 0; ct < 8; ct++) acc[ct] = f32x4{0.f, 0.f, 0.f, 0.f};
#pragma unroll
    for (int kt = 0; kt < 4; kt++) {
        const int k = kt * 32 + quad * 8;
        short8 a = *(const short8*)(hB + (size_t)(r0 + m) * 128 + k);
#pragma unroll
        for (int ct = 0; ct < 8; ct++) {
            short8 bf = *(const short8*)(W + (size_t)(w * 128 + ct * 16 + m) * 128 + k);
            acc[ct] = mfma16(a, bf, acc[ct]);
        }
    }
    float sa[4] = {0.f, 0.f, 0.f, 0.f}, sd[4] = {0.f, 0.f, 0.f, 0.f};
#pragma unroll
    for (int ct = 0; ct < 8; ct++) {
        const int c = ct * 16 + m;
        const float av = asrc[w * 128 + c], dv = adst[w * 128 + c];
#pragma unroll
        for (int r = 0; r < 4; r++) {
            const float v = acc[ct][r];
            xl[(size_t)(r0 + quad * 4 + r) * 512 + c * 4 + w] = f2b(v);
            sa[r] = fmaf(v, av, sa[r]);
            sd[r] = fmaf(v, dv, sd[r]);
        }
    }
#pragma unroll
    for (int o = 1; o < 16; o <<= 1) {
#pragma unroll
        for (int r = 0; r < 4; r++) {
            sa[r] += __shfl_xor(sa[r], o);
            sd[r] += __shfl_xor(sd[r], o);
        }
    }
    if (m == 0) {
#pragma unroll
        for (int r = 0; r < 4; r++) {
            const int node = r0 + quad * 4 + r;
            as_[node * 4 + w] = sa[r];
            ad_[node * 4 + w] = sd[r];
        }
    }
}

// ---------------------------------------------------------------------------
// edge_exp stage: 131072 threads, one (batch,edge) each.
// ---------------------------------------------------------------------------
static __device__ void edge_exp_stage(int idx, const int* ei, const float* ew,
                                      const float* as_, const float* ad_,
                                      const float* se4, float* pexp) {
    const int b = idx >> 14, e = idx & (EE - 1);
    const int src = b * 1024 + ei[e];
    const int dst = b * 1024 + ei[EE + e];
    const float eaw = ew[e];
    const float4 s4 = *(const float4*)(as_ + src * 4);
    const float4 d4 = *(const float4*)(ad_ + dst * 4);
    const float* s = (const float*)&s4;
    const float* d = (const float*)&d4;
    float4 p;
    float* pp = (float*)&p;
#pragma unroll
    for (int h = 0; h < 4; h++) {
        float a = s[h] + d[h] + eaw * se4[h];
        a = (a < 0.f) ? 0.2f * a : a;
        pp[h] = EXP2(fminf(a, 60.f) * L2E);
    }
    *(float4*)(pexp + (size_t)idx * 4) = p;
}

// ---------------------------------------------------------------------------
// gat stage (one (dst,batch) unit per call): single pass with precomputed
// pexp, head-interleaved xl, fused bias/relu/residual/LN (+opt out-proj).
// ---------------------------------------------------------------------------
static __device__ void gat_unit(int v, int lane, float* hF, ushort* hB,
                                const ushort* xl, const float* as_, const float* ad_,
                                const float* pexp, const int* eidx, const int* offs,
                                const int* deg0, const float* loopea, const int* ei,
                                const float* se4, const float* bias,
                                const float* lng, const float* lnb, int relu,
                                int writeOut, const float* oW, const float* ob,
                                float* out) {
    const int b = v >> 10, n = v & 1023;
    const int dg = deg0[n], off = offs[n];

    const float lea = loopea[n];
    const float4 s4 = *(const float4*)(as_ + v * 4);
    const float4 d4 = *(const float4*)(ad_ + v * 4);
    const float* sp = (const float*)&s4;
    const float* dp = (const float*)&d4;
    float den[4], num0[4], num1[4];
    {
        const ushort4 xa = *(const ushort4*)(xl + (size_t)v * 512 + lane * 4);
        const ushort4 xb = *(const ushort4*)(xl + (size_t)v * 512 + (64 + lane) * 4);
        const ushort* xap = (const ushort*)&xa;
        const ushort* xbp = (const ushort*)&xb;
#pragma unroll
        for (int h = 0; h < 4; h++) {
            float a = sp[h] + dp[h] + lea * se4[h];
            a = (a < 0.f) ? 0.2f * a : a;
            const float p = EXP2(fminf(a, 60.f) * L2E);
            den[h] = p;
            num0[h] = p * b2f(xap[h]);
            num1[h] = p * b2f(xbp[h]);
        }
    }
    for (int i = 0; i < dg; i++) {
        const int e = eidx[off + i];
        const int src = b * 1024 + ei[e];
        const float4 p4 = *(const float4*)(pexp + ((size_t)(b << 14) + e) * 4);
        const float* p = (const float*)&p4;
        const ushort4 xa = *(const ushort4*)(xl + (size_t)src * 512 + lane * 4);
        const ushort4 xb = *(const ushort4*)(xl + (size_t)src * 512 + (64 + lane) * 4);
        const ushort* xap = (const ushort*)&xa;
        const ushort* xbp = (const ushort*)&xb;
#pragma unroll
        for (int h = 0; h < 4; h++) {
            den[h] += p[h];
            num0[h] = fmaf(p[h], b2f(xap[h]), num0[h]);
            num1[h] = fmaf(p[h], b2f(xbp[h]), num1[h]);
        }
    }
    float o0 = 0.f, o1 = 0.f;
#pragma unroll
    for (int h = 0; h < 4; h++) {
        const float inv = RCPF(den[h]);
        o0 = fmaf(num0[h], inv, o0);
        o1 = fmaf(num1[h], inv, o1);
    }

    float d0 = o0 * 0.25f + bias[lane];
    float d1 = o1 * 0.25f + bias[64 + lane];
    if (relu) { d0 = fmaxf(d0, 0.f); d1 = fmaxf(d1, 0.f); }
    const float x0 = hF[(size_t)v * 128 + lane] + d0;
    const float x1 = hF[(size_t)v * 128 + 64 + lane] + d1;

    float s = x0 + x1;
#pragma unroll
    for (int o = 32; o; o >>= 1) s += __shfl_xor(s, o);
    const float mu = s * (1.f / 128.f);
    const float e0 = x0 - mu, e1 = x1 - mu;
    float vs = e0 * e0 + e1 * e1;
#pragma unroll
    for (int o = 32; o; o >>= 1) vs += __shfl_xor(vs, o);
    const float r = rsqrtf(vs * (1.f / 128.f) + 1e-5f);
    const float y0 = e0 * r * lng[lane] + lnb[lane];
    const float y1 = e1 * r * lng[64 + lane] + lnb[64 + lane];
    if (writeOut) {
        float t = y0 * oW[lane] + y1 * oW[64 + lane];
#pragma unroll
        for (int o = 32; o; o >>= 1) t += __shfl_xor(t, o);
        if (lane == 0) out[v] = t + ob[0];
    } else {
        hF[(size_t)v * 128 + lane] = y0;
        hF[(size_t)v * 128 + 64 + lane] = y1;
        hB[(size_t)v * 128 + lane] = f2b(y0);
        hB[(size_t)v * 128 + 64 + lane] = f2b(y1);
    }
}

// ---------------------------------------------------------------------------
// THE mega-kernel: all stages, 9 grid barriers, one dispatch.
// ---------------------------------------------------------------------------
__global__ __launch_bounds__(256, 2) void mega_kernel(
    const float* dyn, const float* fcst, const float* sta,
    const int* ei, const float* ew,
    const float* lWih, const float* lWhh, const float* lbih, const float* lbhh,
    const float* sW, const float* sb, const float* fW, const float* fb,
    const float* uW, const float* ub,
    const float* g0W, const float* g0as, const float* g0ad,
    const float* g0We, const float* g0ae, const float* g0b,
    const float* g1W, const float* g1as, const float* g1ad,
    const float* g1We, const float* g1ae, const float* g1b,
    const float* ln0g, const float* ln0b, const float* ln1g, const float* ln1b,
    const float* oW, const float* ob,
    ushort* castB, ushort* zsf, float* hF, ushort* hB, ushort* xl,
    float* asb, float* adb,
    int* deg0, int* offs, float* loopea, int* eidx, float* se,
    int* bar, float* out) {
    const int tid = threadIdx.x;
    const int bid = blockIdx.x;
    const int w = tid >> 6, lane = tid & 63, quad = lane >> 4, m = lane & 15;
    const int wid = bid * 4 + w;
    float* pexp = (float*)zsf;   // overlay: zsf dead after fusion stage

    constexpr int HS = 168;
    __shared__ ushort hbuf[2][16 * HS];
    __shared__ int degL[1024];
    __shared__ float wsL[1024];
    __shared__ int part[256];
    __shared__ float seL[8];

    // ================= Stage 0: cast (blocks 0..510) + prep (block 511) ====
    if (bid < 511) {
        for (int i = bid * 256 + tid; i < O_END; i += 511 * 256) {
            float v;
            if      (i < O_WHH) v = lWih[i - O_WIH];
            else if (i < O_STA) v = lWhh[i - O_WHH];
            else if (i < O_FCS) v = sta[i - O_STA];
            else if (i < O_SW)  v = fcst[i - O_FCS];
            else if (i < O_FW)  v = sW[i - O_SW];
            else if (i < O_UW)  v = fW[i - O_FW];
            else if (i < O_G0W) v = uW[i - O_UW];
            else if (i < O_G1W) v = g0W[i - O_G0W];
            else                v = g1W[i - O_G1W];
            castB[i] = f2b(v);
        }
    } else {
        for (int i = tid; i < 1024; i += 256) { degL[i] = 0; wsL[i] = 0.f; }
        if (tid < 8) seL[tid] = 0.f;
        __syncthreads();
        for (int e = tid; e < EE; e += 256) {
            const int d = ei[EE + e];
            atomicAdd(&degL[d], 1);
            atomicAdd(&wsL[d], ew[e]);
        }
        __syncthreads();
        const int d0 = degL[4 * tid], d1 = degL[4 * tid + 1];
        const int d2 = degL[4 * tid + 2], d3 = degL[4 * tid + 3];
        const int tot = d0 + d1 + d2 + d3;
        part[tid] = tot;
        __syncthreads();
        for (int o = 1; o < 256; o <<= 1) {
            const int v = (tid >= o) ? part[tid - o] : 0;
            __syncthreads();
            part[tid] += v;
            __syncthreads();
        }
        const int base = part[tid] - tot;
        int ex[4];
        ex[0] = base; ex[1] = base + d0; ex[2] = ex[1] + d1; ex[3] = ex[2] + d2;
        const int dd4[4] = {d0, d1, d2, d3};
#pragma unroll
        for (int j = 0; j < 4; j++) {
            const int n = 4 * tid + j;
            offs[n] = ex[j];
            deg0[n] = dd4[j];
            loopea[n] = wsL[n] / fmaxf((float)dd4[j], 1.f);
        }
        __syncthreads();
#pragma unroll
        for (int j = 0; j < 4; j++) degL[4 * tid + j] = ex[j];
        __syncthreads();
        for (int e = tid; e < EE; e += 256) {
            const int dd = ei[EE + e];
            const int slot = atomicAdd(&degL[dd], 1);
            eidx[slot] = e;
        }
        for (int i = tid; i < 1024; i += 256) {
            const int g = i >> 7, k = i & 127, head = g & 3;
            const float* W = (g >> 2) ? g1We : g0We;
            const float* A = (g >> 2) ? g1ae : g0ae;
            atomicAdd(&seL[g], W[head * 128 + k] * A[head * 128 + k]);
        }
        __syncthreads();
        if (tid < 8) se[tid] = seL[tid];
    }
    gridbar(bar);

    // ================= Stage 1: LSTM (exact R4 structure) ==================
    {
        const ushort* Wih = castB + O_WIH;
        const ushort* Whh = castB + O_WHH;
        const int b = bid >> 6;
        const int n0 = (bid & 63) << 4;

        short8 Bf[5][4][2];
        float ci[2], cf[2], cg[2], co[2];
#pragma unroll
        for (int jj = 0; jj < 2; jj++) {
            const int u = (2 * w + jj) * 16 + m;
#pragma unroll
            for (int g = 0; g < 4; g++) {
                const int grow = g * 128 + u;
#pragma unroll
                for (int kt = 0; kt < 4; kt++)
                    Bf[kt][g][jj] = *(const short8*)(Whh + grow * 128 + kt * 32 + quad * 8);
                if (quad < 2) Bf[4][g][jj] = *(const short8*)(Wih + grow * 16 + quad * 8);
                else          Bf[4][g][jj] = short8{0, 0, 0, 0, 0, 0, 0, 0};
            }
            ci[jj] = -L2E * (lbih[u] + lbhh[u]);
            cf[jj] = -L2E * (lbih[128 + u] + lbhh[128 + u]);
            cg[jj] =  T2E * (lbih[256 + u] + lbhh[256 + u]);
            co[jj] = -L2E * (lbih[384 + u] + lbhh[384 + u]);
        }

        float c[2][4];
#pragma unroll
        for (int jj = 0; jj < 2; jj++)
#pragma unroll
            for (int r = 0; r < 4; r++) c[jj][r] = 0.f;

        for (int i = tid; i < 2 * 16 * HS; i += 256) ((ushort*)hbuf)[i] = 0;
        __syncthreads();

        const int xn = tid >> 4, xf = tid & 15;
        const size_t xbase = (size_t)b * TT * NN * FD_ + (size_t)(n0 + xn) * FD_ + xf;
        hbuf[0][xn * HS + 128 + xf] = f2b(dyn[xbase]);
        float xv = dyn[xbase + (size_t)NN * FD_];
        __syncthreads();

        for (int t = 0; t < TT; t++) {
            const ushort* rb = hbuf[t & 1];
            ushort* wb = hbuf[(t + 1) & 1];
            if (t + 1 < TT) wb[xn * HS + 128 + xf] = f2b(xv);
            if (t + 2 < TT) xv = dyn[xbase + (size_t)(t + 2) * NN * FD_];

            f32x4 acc[4][2];
#pragma unroll
            for (int g = 0; g < 4; g++)
#pragma unroll
                for (int jj = 0; jj < 2; jj++) acc[g][jj] = f32x4{0.f, 0.f, 0.f, 0.f};
#pragma unroll
            for (int kt = 0; kt < 5; kt++) {
                short8 a = *(const short8*)&rb[m * HS + kt * 32 + quad * 8];
#pragma unroll
                for (int g = 0; g < 4; g++)
#pragma unroll
                    for (int jj = 0; jj < 2; jj++)
                        acc[g][jj] = mfma16(a, Bf[kt][g][jj], acc[g][jj]);
            }

#pragma unroll
            for (int jj = 0; jj < 2; jj++) {
                const int u = (2 * w + jj) * 16 + m;
#pragma unroll
                for (int r = 0; r < 4; r++) {
                    const int n = quad * 4 + r;
                    const float Di = 1.f + EXP2(fmaf(acc[0][jj][r], -L2E, ci[jj]));
                    const float Df = 1.f + EXP2(fmaf(acc[1][jj][r], -L2E, cf[jj]));
                    const float Eg = EXP2(fmaf(acc[2][jj][r], T2E, cg[jj]));
                    const float Do = 1.f + EXP2(fmaf(acc[3][jj][r], -L2E, co[jj]));
                    const float R  = RCPF(Di * (1.f + Eg));
                    const float sf = RCPF(Df);
                    const float cc = fmaf(sf, c[jj][r], (Eg - 1.f) * R);
                    c[jj][r] = cc;
                    const float Ec = EXP2(T2E * cc);
                    const float h = (Ec - 1.f) * RCPF(Do * (1.f + Ec));
                    wb[n * HS + u] = f2b_fast(h);
                    if (t == TT - 1) zsf[(size_t)(bid * 16 + n) * 384 + u] = f2b_fast(h);
                }
            }
            __syncthreads();
        }
    }
    gridbar(bar);

    // ================= Stage 2: s/f GEMMs (8192 tiles / 2048 waves) ========
    {
        const ushort* staB = castB + O_STA;
        const ushort* fcsB = castB + O_FCS;
        const ushort* sWB  = castB + O_SW;
        const ushort* fWB  = castB + O_FW;
        const short8 z8 = short8{0, 0, 0, 0, 0, 0, 0, 0};
        for (int t = wid; t < 8192; t += 2048) {
            short8 a, bf;
            int r0, c0, ocol;
            const float* bias;
            if (t < 4096) {
                r0 = (t >> 3) * 16; c0 = (t & 7) * 16; ocol = 128; bias = sb;
                a  = *(const short8*)(staB + (size_t)(r0 + m) * 32 + quad * 8);
                bf = *(const short8*)(sWB + (size_t)(c0 + m) * 32 + quad * 8);
            } else {
                const int tt = t - 4096;
                r0 = (tt >> 3) * 16; c0 = (tt & 7) * 16; ocol = 256; bias = fb;
                a  = (quad == 0) ? *(const short8*)(fcsB + (size_t)(r0 + m) * 8) : z8;
                bf = (quad == 0) ? *(const short8*)(fWB + (size_t)(c0 + m) * 8) : z8;
            }
            f32x4 acc = mfma16(a, bf, f32x4{0.f, 0.f, 0.f, 0.f});
            const float bv = bias[c0 + m];
#pragma unroll
            for (int r = 0; r < 4; r++) {
                const int row = r0 + quad * 4 + r;
                zsf[(size_t)row * 384 + ocol + c0 + m] = f2b(fmaxf(acc[r] + bv, 0.f));
            }
        }
    }
    gridbar(bar);

    // ================= Stage 3: fusion GEMM (4096 tiles / 2048 waves) ======
    {
        const ushort* uWB = castB + O_UW;
        for (int t = wid; t < 4096; t += 2048) {
            const int r0 = (t >> 3) * 16, c0 = (t & 7) * 16;
            f32x4 acc = f32x4{0.f, 0.f, 0.f, 0.f};
#pragma unroll
            for (int kt = 0; kt < 12; kt++) {
                const int k = kt * 32 + quad * 8;
                short8 a  = *(const short8*)(zsf + (size_t)(r0 + m) * 384 + k);
                short8 bf = *(const short8*)(uWB + (size_t)(c0 + m) * 384 + k);
                acc = mfma16(a, bf, acc);
            }
            const int col = c0 + m;
            const float bv = ub[col];
#pragma unroll
            for (int r = 0; r < 4; r++) {
                const int row = r0 + quad * 4 + r;
                const float v = fmaxf(acc[r] + bv, 0.f);
                hB[(size_t)row * 128 + col] = f2b(v);
                hF[(size_t)row * 128 + col] = v;
            }
        }
    }
    gridbar(bar);

    // ================= Stage 4-6: hop 0 ====================================
    gemmatt_stage(bid, tid, hB, castB + O_G0W, g0as, g0ad, xl, asb, adb);
    gridbar(bar);
    edge_exp_stage(bid * 256 + tid, ei, ew, asb, adb, se, pexp);
    gridbar(bar);
    for (int v = wid; v < 8192; v += 2048)
        gat_unit(v, lane, hF, hB, xl, asb, adb, pexp, eidx, offs, deg0, loopea,
                 ei, se, g0b, ln0g, ln0b, 1, 0, oW, ob, out);
    gridbar(bar);

    // ================= Stage 7-9: hop 1 + output ===========================
    gemmatt_stage(bid, tid, hB, castB + O_G1W, g1as, g1ad, xl, asb, adb);
    gridbar(bar);
    edge_exp_stage(bid * 256 + tid, ei, ew, asb, adb, se + 4, pexp);
    gridbar(bar);
    for (int v = wid; v < 8192; v += 2048)
        gat_unit(v, lane, hF, hB, xl, asb, adb, pexp, eidx, offs, deg0, loopea,
                 ei, se + 4, g1b, ln1g, ln1b, 0, 1, oW, ob, out);
}

// ---------------------------------------------------------------------------
extern "C" void kernel_launch(void* const* d_in, const int* in_sizes, int n_in,
                              void* d_out, int out_size, void* d_ws, size_t ws_size,
                              hipStream_t stream) {
    const float* dyn  = (const float*)d_in[0];
    const float* fcst = (const float*)d_in[1];
    const float* sta  = (const float*)d_in[2];
    const int*   ei   = (const int*)d_in[3];
    const float* ew   = (const float*)d_in[4];
    const float* lWih = (const float*)d_in[5];
    const float* lWhh = (const float*)d_in[6];
    const float* lbih = (const float*)d_in[7];
    const float* lbhh = (const float*)d_in[8];
    const float* sW = (const float*)d_in[9];
    const float* sb = (const float*)d_in[10];
    const float* fW = (const float*)d_in[11];
    const float* fb = (const float*)d_in[12];
    const float* uW = (const float*)d_in[13];
    const float* ub = (const float*)d_in[14];
    const float* g0W  = (const float*)d_in[15];
    const float* g0as = (const float*)d_in[16];
    const float* g0ad = (const float*)d_in[17];
    const float* g0ae = (const float*)d_in[18];
    const float* g0We = (const float*)d_in[19];
    const float* g0b  = (const float*)d_in[20];
    const float* g1W  = (const float*)d_in[21];
    const float* g1as = (const float*)d_in[22];
    const float* g1ad = (const float*)d_in[23];
    const float* g1ae = (const float*)d_in[24];
    const float* g1We = (const float*)d_in[25];
    const float* g1b  = (const float*)d_in[26];
    const float* ln0g = (const float*)d_in[27];
    const float* ln0b = (const float*)d_in[28];
    const float* ln1g = (const float*)d_in[29];
    const float* ln1b = (const float*)d_in[30];
    const float* oW = (const float*)d_in[31];
    const float* ob = (const float*)d_in[32];

    char* p = (char*)d_ws;
    ushort* castB = (ushort*)p; p += (size_t)O_END * 2 + 512;
    ushort* zsf = (ushort*)p;  p += (size_t)BN_ * 384 * 2;
    float*  hF  = (float*)p;   p += (size_t)BN_ * 128 * 4;
    ushort* hB  = (ushort*)p;  p += (size_t)BN_ * 128 * 2;
    ushort* xl  = (ushort*)p;  p += (size_t)BN_ * 512 * 2;
    float*  asb = (float*)p;   p += (size_t)BN_ * 4 * 4;
    float*  adb = (float*)p;   p += (size_t)BN_ * 4 * 4;
    int*    deg0   = (int*)p;   p += 4096;
    int*    offs   = (int*)p;   p += 4096;
    float*  loopea = (float*)p; p += 4096;
    int*    eidx   = (int*)p;   p += (size_t)EE * 4;
    float*  se     = (float*)p; p += 256;
    int*    bar    = (int*)p;   p += 256;

    hipMemsetAsync(bar, 0, 256, stream);
    mega_kernel<<<NBLK, 256, 0, stream>>>(
        dyn, fcst, sta, ei, ew, lWih, lWhh, lbih, lbhh,
        sW, sb, fW, fb, uW, ub,
        g0W, g0as, g0ad, g0We, g0ae, g0b,
        g1W, g1as, g1ad, g1We, g1ae, g1b,
        ln0g, ln0b, ln1g, ln1b, oW, ob,
        castB, zsf, hF, hB, xl, asb, adb,
        deg0, offs, loopea, eidx, se, bar, (float*)d_out);
}